// Round 7
// baseline (243.368 us; speedup 1.0000x reference)
//
#include <hip/hip_runtime.h>
#include <hip/hip_bf16.h>
#include <math.h>

// B=8, S=512, HID=1024, NH=16, D=64, SPAN=512
// scale = 1/sqrt(64*3)  (pre-applied to Q and pq in proj epilogue)
#define SCALE 0.07216878364870323f
#define NEG_BIG -1e30f

typedef __attribute__((ext_vector_type(8))) short bf16x8;
typedef __attribute__((ext_vector_type(4))) short bf16x4;
typedef __attribute__((ext_vector_type(4))) float f32x4;
#define MFMA_BF16 __builtin_amdgcn_mfma_f32_16x16x32_bf16

static __device__ __forceinline__ float bf2f(__hip_bfloat16 x) { return __bfloat162float(x); }
static __device__ __forceinline__ __hip_bfloat16 f2bf(float x) { return __float2bfloat16(x); }
static __device__ __forceinline__ short f2bs(float x) {
  union { __hip_bfloat16 b; short s; } u; u.b = __float2bfloat16(x); return u.s;
}
static __device__ __forceinline__ float s2f(short v) {
  union { float f; unsigned u; } x; x.u = ((unsigned)(unsigned short)v) << 16; return x.f;
}
static __device__ __forceinline__ bf16x4 cvt4(float4 f) {
  bf16x4 r; r[0] = f2bs(f.x); r[1] = f2bs(f.y); r[2] = f2bs(f.z); r[3] = f2bs(f.w);
  return r;
}
static __device__ __forceinline__ bf16x8 ldg8(const __hip_bfloat16* p) {
  return *(const bf16x8*)p;
}
// async global->LDS, 16B per lane; LDS dest = wave-uniform base + lane*16
static __device__ __forceinline__ void gl_lds16(const __hip_bfloat16* g, __hip_bfloat16* l) {
  __builtin_amdgcn_global_load_lds(
      (const __attribute__((address_space(1))) void*)g,
      (__attribute__((address_space(3))) void*)l, 16, 0, 0);
}

// ---------------------------------------------------------------------------
// cvt: fp32 -> bf16 for SMALL tensors only (weights + rel).  6 jobs.
// q,k,v conversion is fused into proj staging (they are read exactly once).
// ---------------------------------------------------------------------------
struct CvtJob { const float* src; __hip_bfloat16* dst; int n4; };
struct CvtArgs { CvtJob j[6]; };

__global__ __launch_bounds__(256) void cvt_kernel(CvtArgs a) {
  const CvtJob jb = a.j[blockIdx.y];
  const float4* s = (const float4*)jb.src;
  bf16x4* d = (bf16x4*)jb.dst;
  const int stride = gridDim.x * 256;
  for (int i = blockIdx.x * 256 + threadIdx.x; i < jb.n4; i += stride)
    d[i] = cvt4(s[i]);
}

// ---------------------------------------------------------------------------
// proj (256^2, BK=64 dbuf, single-barrier/tile): C[M,N] = (A@W^T + bias)*osc.
// R5 tile/read layout (XOR swizzle, 0 conflicts).  Per job at most ONE
// operand is fp32 (aF32/wF32): that side is reg-staged (T14 async-split:
// float4 loads issued one tile early -> cvt -> ds_write_b128 into the SAME
// swizzled layout); the bf16 side uses async global_load_lds.  One
// __syncthreads per K-tile (its vmcnt/lgkm drain lands after a full compute
// phase of slack over every in-flight load).
// ---------------------------------------------------------------------------
struct Gemm { const void* A; const void* W; const float* bias; __hip_bfloat16* out;
              int mode; int mBits; int nBlk; float oscale; int aF32; int wF32; };
struct ProjArgs { Gemm g[5]; };

// bf16 side: stage full 256x64 tile via gload_lds (4 issues/thread).
// layout: dest row = rowbase + (lane>>3), dest chunk = lane&7 holds global
// chunk (lane&7)^(row&7)  [XOR swizzle via pre-swizzled source]
static __device__ __forceinline__ void stage_bf16(const __hip_bfloat16* gpanel, int kcol,
                                                  __hip_bfloat16* ltile, int wave, int lane) {
  const int r = lane >> 3;
  const int chunk = (lane & 7) ^ r;
#pragma unroll
  for (int hc = 0; hc < 4; hc++) {
    const int rowbase = hc * 64 + wave * 8;
    gl_lds16(gpanel + (size_t)(rowbase + r) * 1024 + kcol + chunk * 8,
             ltile + (size_t)rowbase * 64);
  }
}

// f32 side, step 1: issue 8 float4 loads (same coords as stage_bf16, 32B per
// 8-elem chunk)
static __device__ __forceinline__ void load_f32(const float* gpanel, int kcol,
                                                float4* st, int wave, int lane) {
  const int r = lane >> 3;
  const int chunk = (lane & 7) ^ r;
#pragma unroll
  for (int hc = 0; hc < 4; hc++) {
    const int row = hc * 64 + wave * 8 + r;
    const float* src = gpanel + (size_t)row * 1024 + kcol + chunk * 8;
    st[hc * 2 + 0] = *(const float4*)(src);
    st[hc * 2 + 1] = *(const float4*)(src + 4);
  }
}

// f32 side, step 2: convert + ds_write_b128 into the identical layout
static __device__ __forceinline__ void write_f32(__hip_bfloat16* ltile,
                                                 const float4* st, int wave, int lane) {
#pragma unroll
  for (int hc = 0; hc < 4; hc++) {
    const int rowbase = hc * 64 + wave * 8;
    const float4 lo = st[hc * 2 + 0], hi = st[hc * 2 + 1];
    bf16x8 v;
    v[0] = f2bs(lo.x); v[1] = f2bs(lo.y); v[2] = f2bs(lo.z); v[3] = f2bs(lo.w);
    v[4] = f2bs(hi.x); v[5] = f2bs(hi.y); v[6] = f2bs(hi.z); v[7] = f2bs(hi.w);
    *(bf16x8*)(ltile + (size_t)rowbase * 64 + lane * 8) = v;
  }
}

__global__ __launch_bounds__(512, 2) void proj_kernel(ProjArgs pa) {
  const Gemm g = pa.g[blockIdx.y];
  if ((int)blockIdx.x >= g.nBlk) return;
  __shared__ __hip_bfloat16 As[2][256][64];   // 64 KiB
  __shared__ __hip_bfloat16 Ws[2][256][64];   // 64 KiB

  const int bid = blockIdx.x;
  const int m0 = (bid & ((1 << g.mBits) - 1)) * 256;
  const int n0 = (bid >> g.mBits) * 256;
  const int tid = threadIdx.x;
  const int wave = tid >> 6, lane = tid & 63;
  const int q16 = lane >> 4, l16 = lane & 15;
  const int wr = wave >> 2, wc = wave & 3;     // 2 (M) x 4 (N) wave grid
  const int l7 = l16 & 7;

  const bool af32 = (g.aF32 != 0), wf32 = (g.wF32 != 0);
  const float* Ag32 = (const float*)g.A + (size_t)m0 * 1024;
  const float* Wg32 = (const float*)g.W + (size_t)n0 * 1024;
  const __hip_bfloat16* Ag16 = (const __hip_bfloat16*)g.A + (size_t)m0 * 1024;
  const __hip_bfloat16* Wg16 = (const __hip_bfloat16*)g.W + (size_t)n0 * 1024;

  f32x4 acc[8][4] = {};
  float4 stF[8];   // staging regs for the (at most one) f32 side

  // prologue: stage tile 0; f32 side also loads tile 1 into regs
  if (af32) {
    load_f32(Ag32, 0, stF, wave, lane);
    write_f32(&As[0][0][0], stF, wave, lane);
    load_f32(Ag32, 64, stF, wave, lane);
  } else {
    stage_bf16(Ag16, 0, &As[0][0][0], wave, lane);
  }
  if (wf32) {
    load_f32(Wg32, 0, stF, wave, lane);
    write_f32(&Ws[0][0][0], stF, wave, lane);
    load_f32(Wg32, 64, stF, wave, lane);
  } else {
    stage_bf16(Wg16, 0, &Ws[0][0][0], wave, lane);
  }

  for (int t = 0; t < 16; ++t) {
    __syncthreads();   // tile-t staging visible (vmcnt/lgkm drained + barrier)
    // stage tile t+1 into buf^1; f32 side writes regs then reloads for t+2
    if (t + 1 < 16) {
      const int kn = (t + 1) * 64;
      if (af32) {
        write_f32(&As[(t + 1) & 1][0][0], stF, wave, lane);
        if (t + 2 < 16) load_f32(Ag32, (t + 2) * 64, stF, wave, lane);
      } else {
        stage_bf16(Ag16, kn, &As[(t + 1) & 1][0][0], wave, lane);
      }
      if (wf32) {
        write_f32(&Ws[(t + 1) & 1][0][0], stF, wave, lane);
        if (t + 2 < 16) load_f32(Wg32, (t + 2) * 64, stF, wave, lane);
      } else {
        stage_bf16(Wg16, kn, &Ws[(t + 1) & 1][0][0], wave, lane);
      }
    }
    // compute tile t (R5 pattern: 2 kh phases, 64 MFMA/wave)
    const __hip_bfloat16* Ac = &As[t & 1][0][0];
    const __hip_bfloat16* Wc = &Ws[t & 1][0][0];
#pragma unroll
    for (int kh = 0; kh < 2; kh++) {
      const int csw = ((kh * 4 + q16) ^ l7) * 8;   // swizzled read column
      bf16x8 bw[4];
#pragma unroll
      for (int ni = 0; ni < 4; ni++)
        bw[ni] = *(const bf16x8*)(Wc + (size_t)(wc * 64 + ni * 16 + l16) * 64 + csw);
#pragma unroll
      for (int mh = 0; mh < 2; mh++) {
        bf16x8 af[4];
#pragma unroll
        for (int mi = 0; mi < 4; mi++)
          af[mi] = *(const bf16x8*)(Ac + (size_t)(wr * 128 + mh * 64 + mi * 16 + l16) * 64 + csw);
        __builtin_amdgcn_s_setprio(1);
#pragma unroll
        for (int ni = 0; ni < 4; ni++)
#pragma unroll
          for (int mi = 0; mi < 4; mi++)
            acc[mh * 4 + mi][ni] =
                MFMA_BF16(af[mi], bw[ni], acc[mh * 4 + mi][ni], 0, 0, 0);
        __builtin_amdgcn_s_setprio(0);
      }
    }
  }

#pragma unroll
  for (int ni = 0; ni < 4; ni++) {
    const int n = n0 + wc * 64 + ni * 16 + l16;
#pragma unroll
    for (int mi = 0; mi < 8; mi++) {
#pragma unroll
      for (int rr = 0; rr < 4; rr++) {
        const int m = m0 + wr * 128 + mi * 16 + q16 * 4 + rr;
        float val = acc[mi][ni][rr];
        size_t oidx;
        if (g.mode == 0) {
          val = (val + g.bias[n]) * g.oscale;
          const int b = m >> 9, s = m & 511;
          const int h = n >> 6, d = n & 63;
          oidx = ((size_t)((b * 16 + h) * 512 + s)) * 64 + d;
        } else if (g.mode == 1) {
          // operand-swapped V GEMM: m = hid (h,d), n = (b,s)
          val = (val + g.bias[m]) * g.oscale;
          const int b = n >> 9, s = n & 511;
          const int h = m >> 6, d = m & 63;
          oidx = ((size_t)((b * 16 + h) * 64 + d)) * 512 + s;
        } else {
          val = (val + g.bias[n]) * g.oscale;
          const int h = n >> 6, d = n & 63;
          oidx = ((size_t)(h * 512 + m)) * 64 + d;
        }
        g.out[oidx] = f2bf(val);
      }
    }
  }
}

// ---------------------------------------------------------------------------
// attn: fused online-softmax version (flash-style), 3 blocks/CU (round 5).
// ---------------------------------------------------------------------------
__global__ __launch_bounds__(256) void attn_kernel(
    const __hip_bfloat16* __restrict__ ql,   // [B*NH,512,64] (pre-scaled)
    const __hip_bfloat16* __restrict__ kl,   // [B*NH,512,64]
    const __hip_bfloat16* __restrict__ vlT,  // [B*NH,64,512]
    const __hip_bfloat16* __restrict__ pk,   // [NH,512,64]  (rows = jj = q-k)
    const __hip_bfloat16* __restrict__ pq,   // [NH,512,64]  (pre-scaled)
    float* __restrict__ out)                 // [B,S,HID] fp32
{
  __shared__ __align__(16) __hip_bfloat16 pool[2][64][72];  // kl rows 0-31, pk rows 32-63
  __shared__ __align__(16) __hip_bfloat16 pqs[2][32][72];   // pq windows
  __shared__ __align__(16) float qkbuf[32][36];             // qk term, f32
  __shared__ __align__(16) __hip_bfloat16 cpb[2][32][68];   // cp: [par][q][jj]
  __shared__ __align__(16) __hip_bfloat16 pT[64][36];       // p2c: [dlt+32][k]
  __shared__ __align__(16) __hip_bfloat16 ptile[32][40];    // P tile (MFMA-A layout)
  __shared__ __align__(16) __hip_bfloat16 vt[64][40];       // V^T tile [d][k]
  __shared__ float mred[32];
  __shared__ float rsum[32];
  // total 53,504 B -> 3 blocks/CU

  const int bid = blockIdx.x;
  const int qt = 15 - (bid >> 7);
  const int bh = bid & 127;
  const int h = bh & 15, b = bh >> 4;
  const int q0 = qt * 32;

  const __hip_bfloat16* qlp = ql + (size_t)bh * 512 * 64;
  const __hip_bfloat16* klp = kl + (size_t)bh * 512 * 64;
  const __hip_bfloat16* vtp = vlT + (size_t)bh * 64 * 512;
  const __hip_bfloat16* pkp = pk + (size_t)h * 512 * 64;
  const __hip_bfloat16* pqp = pq + (size_t)h * 512 * 64;

  const int tid = threadIdx.x, wave = tid >> 6, lane = tid & 63;
  const int q16 = lane >> 4, l16 = lane & 15;
  const int wr = wave & 1, wc = wave >> 1;   // PV wave grid

  // ql B-fragments (cols of the swapped score MFMAs), loop-invariant
  bf16x8 qlB[2][2];
#pragma unroll
  for (int ksi = 0; ksi < 2; ksi++)
#pragma unroll
    for (int bq = 0; bq < 2; bq++)
      qlB[ksi][bq] = ldg8(qlp + (size_t)(q0 + bq * 16 + l16) * 64 + ksi * 32 + q16 * 8);

  // zero pqs[1] (window "-1" for it=0; feeds pT rows 0..31, masked-only)
  {
    int4 z = {0, 0, 0, 0};
    *(int4*)(&pqs[1][tid >> 3][(tid & 7) * 8]) = z;
  }

  const int kEnd = q0 + 32;
  const int nIter = kEnd >> 5;

  const int sr = tid >> 3, sseg = tid & 7;
  const int vr = tid >> 2, vs = tid & 3;
  int4 rKv, rPKv, rPQv, rVt;
  {
    rKv  = ((const int4*)(klp + (size_t)(q0 + sr) * 64))[sseg];
    rPKv = ((const int4*)(pkp + (size_t)(0 + sr) * 64))[sseg];
    rPQv = ((const int4*)(pqp + (size_t)(0 + sr) * 64))[sseg];
    rVt  = ((const int4*)(vtp + (size_t)vr * 512 + q0))[vs];
  }

  const int aq = tid >> 3;           // assembly q-row (fixed per thread)
  const int kb = (tid & 7) * 4;      // assembly k-quad base
  float m_old = -INFINITY, s_part = 0.f;
  f32x4 octx[2] = {};

  for (int it = 0; it < nIter; ++it) {
    const int k0 = q0 - it * 32;
    const int par = it & 1;
    // --- region1: staging + global prefetch for it+1 ---
    *(int4*)(&pool[par][sr][sseg * 8])      = rKv;
    *(int4*)(&pool[par][32 + sr][sseg * 8]) = rPKv;
    *(int4*)(&pqs[par][sr][sseg * 8])       = rPQv;
    if (it + 1 < nIter) {
      const int k0n = k0 - 32, jbn = (it + 1) * 32;
      rKv  = ((const int4*)(klp + (size_t)(k0n + sr) * 64))[sseg];
      rPKv = ((const int4*)(pkp + (size_t)(jbn + sr) * 64))[sseg];
      rPQv = ((const int4*)(pqp + (size_t)(jbn + sr) * 64))[sseg];
    }
    __syncthreads();   // barA

    // --- region2: wave-specialized score MFMAs + C-writes ---
    const int arb = (wave == 1) ? 32 : 0;
    f32x4 a4[2][2] = {};
    __builtin_amdgcn_s_setprio(1);
#pragma unroll
    for (int ksi = 0; ksi < 2; ksi++) {
      const int ko = ksi * 32 + q16 * 8;
      bf16x8 Af0 = *(const bf16x8*)(&pool[par][arb + l16][ko]);
      bf16x8 Af1 = *(const bf16x8*)(&pool[par][arb + 16 + l16][ko]);
      bf16x8 Bf0, Bf1;
      if (wave < 2) {
        Bf0 = qlB[ksi][0];
        Bf1 = qlB[ksi][1];
      } else {
        const int ps = (wave == 2) ? (par ^ 1) : par;
        Bf0 = *(const bf16x8*)(&pqs[ps][l16][ko]);
        Bf1 = *(const bf16x8*)(&pqs[ps][16 + l16][ko]);
      }
      a4[0][0] = MFMA_BF16(Af0, Bf0, a4[0][0], 0, 0, 0);
      a4[0][1] = MFMA_BF16(Af0, Bf1, a4[0][1], 0, 0, 0);
      a4[1][0] = MFMA_BF16(Af1, Bf0, a4[1][0], 0, 0, 0);
      a4[1][1] = MFMA_BF16(Af1, Bf1, a4[1][1], 0, 0, 0);
    }
    __builtin_amdgcn_s_setprio(0);
    if (wave == 0) {
#pragma unroll
      for (int a = 0; a < 2; a++)
#pragma unroll
        for (int bq = 0; bq < 2; bq++)
          *(f32x4*)(&qkbuf[bq * 16 + l16][a * 16 + q16 * 4]) = a4[a][bq];
    } else if (wave == 1) {
#pragma unroll
      for (int a = 0; a < 2; a++)
#pragma unroll
        for (int bq = 0; bq < 2; bq++) {
          bf16x4 v;
#pragma unroll
          for (int r = 0; r < 4; r++) v[r] = f2bs(a4[a][bq][r]);
          const int q = bq * 16 + l16, jr = a * 16 + q16 * 4;
          *(bf16x4*)(&cpb[par][q][32 + jr]) = v;      // window it (hi)
          *(bf16x4*)(&cpb[par ^ 1][q][jr]) = v;       // dup -> lo of it+1
        }
    } else {
      const int rb = (wave == 3) ? 32 : 0;
#pragma unroll
      for (int a = 0; a < 2; a++)
#pragma unroll
        for (int bq = 0; bq < 2; bq++) {
          bf16x4 v;
#pragma unroll
          for (int r = 0; r < 4; r++) v[r] = f2bs(a4[a][bq][r]);
          *(bf16x4*)(&pT[rb + bq * 16 + l16][a * 16 + q16 * 4]) = v;
        }
    }
    __syncthreads();   // barB

    // --- region3: assembly in regs + online softmax + P/vt staging ---
    {
      const f32x4 qk4 = *(const f32x4*)(&qkbuf[aq][kb]);
      float v[4];
      float tmax = -INFINITY;
#pragma unroll
      for (int j = 0; j < 4; j++) {
        const int dlt = aq - (kb + j);
        v[j] = qk4[j] + bf2f(cpb[par][aq][dlt + 32]) + bf2f(pT[dlt + 32][kb + j]);
        if ((it == 0) && (dlt < 0)) v[j] = -INFINITY;   // causal mask
        else tmax = fmaxf(tmax, v[j]);
      }
      tmax = fmaxf(tmax, __shfl_xor(tmax, 1));
      tmax = fmaxf(tmax, __shfl_xor(tmax, 2));
      tmax = fmaxf(tmax, __shfl_xor(tmax, 4));
      const float m_new = fmaxf(m_old, tmax);
      const float f = __expf(m_old - m_new);   // 0 at it=0 (m_old=-inf)
      bf16x4 pv4;
      float psum = 0.f;
#pragma unroll
      for (int j = 0; j < 4; j++) {
        const float p = __expf(v[j] - m_new);  // masked -> exp(-inf)=0
        pv4[j] = f2bs(p);
        psum += p;
      }
      s_part = s_part * f + psum;
      m_old = m_new;
      *(bf16x4*)(&ptile[aq][kb]) = pv4;
      if ((tid & 7) == 0) mred[aq] = f;
    }
    {  // V^T tile staging (single-buffered; protected by barC..barB window)
      *(int4*)(&vt[vr][vs * 8]) = rVt;
      if (it + 1 < nIter)
        rVt = ((const int4*)(vtp + (size_t)vr * 512 + (k0 - 32)))[vs];
    }
    __syncthreads();   // barC

    // --- region4: PV with online rescale ---
    {
      float fr[4];
#pragma unroll
      for (int rr = 0; rr < 4; rr++) fr[rr] = mred[wr * 16 + q16 * 4 + rr];
      bf16x8 af = *(const bf16x8*)(&ptile[wr * 16 + l16][q16 * 8]);
      __builtin_amdgcn_s_setprio(1);
#pragma unroll
      for (int cs = 0; cs < 2; cs++) {
        bf16x8 bv = *(const bf16x8*)(&vt[wc * 32 + cs * 16 + l16][q16 * 8]);
        f32x4 c = octx[cs];
#pragma unroll
        for (int rr = 0; rr < 4; rr++) c[rr] *= fr[rr];
        octx[cs] = MFMA_BF16(af, bv, c, 0, 0, 0);
      }
      __builtin_amdgcn_s_setprio(0);
    }
  }

  // rowsum reduce (8 threads per row, consecutive lanes)
  {
    float s = s_part;
    s += __shfl_xor(s, 1);
    s += __shfl_xor(s, 2);
    s += __shfl_xor(s, 4);
    if ((tid & 7) == 0) rsum[aq] = s;
  }
  __syncthreads();

  for (int cs = 0; cs < 2; cs++) {
    const int d = wc * 32 + cs * 16 + l16;
    for (int rr = 0; rr < 4; rr++) {
      const int qh = wr * 16 + q16 * 4 + rr;
      const float val = octx[cs][rr] / rsum[qh];
      out[((size_t)(b * 512 + q0 + qh)) * 1024 + h * 64 + d] = val;
    }
  }
}

// ---------------------------------------------------------------------------
extern "C" void kernel_launch(void* const* d_in, const int* in_sizes, int n_in,
                              void* d_out, int out_size, void* d_ws, size_t ws_size,
                              hipStream_t stream) {
  const float* q   = (const float*)d_in[0];
  const float* k   = (const float*)d_in[1];
  const float* v   = (const float*)d_in[2];
  // d_in[3] = attention_mask: deterministic causal tril -> not read
  const float* Wq  = (const float*)d_in[4];
  const float* bq  = (const float*)d_in[5];
  const float* Wk  = (const float*)d_in[6];
  const float* bk  = (const float*)d_in[7];
  const float* Wv  = (const float*)d_in[8];
  const float* bv  = (const float*)d_in[9];
  const float* Wpk = (const float*)d_in[10];
  const float* bpk = (const float*)d_in[11];
  const float* Wpq = (const float*)d_in[12];
  const float* bpq = (const float*)d_in[13];
  const float* rel = (const float*)d_in[14];
  float* out = (float*)d_out;

  char* ws = (char*)d_ws;
  const size_t MB = 1u << 20;
  __hip_bfloat16* bWq  = (__hip_bfloat16*)(ws + 24 * MB);
  __hip_bfloat16* bWk  = (__hip_bfloat16*)(ws + 26 * MB);
  __hip_bfloat16* bWv  = (__hip_bfloat16*)(ws + 28 * MB);
  __hip_bfloat16* bWpk = (__hip_bfloat16*)(ws + 30 * MB);
  __hip_bfloat16* bWpq = (__hip_bfloat16*)(ws + 32 * MB);
  __hip_bfloat16* brel = (__hip_bfloat16*)(ws + 34 * MB);
  __hip_bfloat16* wql  = (__hip_bfloat16*)(ws + 35 * MB);
  __hip_bfloat16* wkl  = (__hip_bfloat16*)(ws + 43 * MB);
  __hip_bfloat16* wvlT = (__hip_bfloat16*)(ws + 51 * MB);
  __hip_bfloat16* wpk  = (__hip_bfloat16*)(ws + 59 * MB);
  __hip_bfloat16* wpq  = (__hip_bfloat16*)(ws + 60 * MB);

  CvtArgs ca;
  ca.j[0] = { Wq,  bWq,  1048576 / 4 };
  ca.j[1] = { Wk,  bWk,  1048576 / 4 };
  ca.j[2] = { Wv,  bWv,  1048576 / 4 };
  ca.j[3] = { Wpk, bWpk, 1048576 / 4 };
  ca.j[4] = { Wpq, bWpq, 1048576 / 4 };
  ca.j[5] = { rel + (size_t)512 * 1024, brel, 524288 / 4 };
  cvt_kernel<<<dim3(256, 6), 256, 0, stream>>>(ca);

  ProjArgs pj;
  // aF32/wF32 flag the fp32 operand (conversion fused into proj staging)
  pj.g[0] = { q,    bWq,  bq,  wql,  0, 4, 64, SCALE, 1, 0 };  // Q pre-scaled
  pj.g[1] = { k,    bWk,  bk,  wkl,  0, 4, 64, 1.0f,  1, 0 };
  pj.g[2] = { bWv,  v,    bv,  wvlT, 1, 2, 64, 1.0f,  0, 1 };  // operand-swapped V
  pj.g[3] = { brel, bWpk, bpk, wpk,  2, 1, 8,  1.0f,  0, 0 };
  pj.g[4] = { brel, bWpq, bpq, wpq,  2, 1, 8,  SCALE, 0, 0 };  // pq pre-scaled
  proj_kernel<<<dim3(64, 5), 512, 0, stream>>>(pj);

  attn_kernel<<<2048, 256, 0, stream>>>(wql, wkl, wvlT, wpk, wpq, out);
}

// Round 9
// 231.369 us; speedup vs baseline: 1.0519x; 1.0519x over previous
//
#include <hip/hip_runtime.h>
#include <hip/hip_bf16.h>
#include <math.h>

// B=8, S=512, HID=1024, NH=16, D=64, SPAN=512
// scale = 1/sqrt(64*3)  (pre-applied to Q and pq in proj epilogue)
#define SCALE 0.07216878364870323f
#define NEG_BIG -1e30f

typedef __attribute__((ext_vector_type(8))) short bf16x8;
typedef __attribute__((ext_vector_type(4))) short bf16x4;
typedef __attribute__((ext_vector_type(4))) float f32x4;
#define MFMA_BF16 __builtin_amdgcn_mfma_f32_16x16x32_bf16

#define BARX()   asm volatile("s_barrier" ::: "memory")
#define VMCNT0() asm volatile("s_waitcnt vmcnt(0)" ::: "memory")
#define LGKM0()  do { asm volatile("s_waitcnt lgkmcnt(0)" ::: "memory"); \
                      __builtin_amdgcn_sched_barrier(0); } while (0)

static __device__ __forceinline__ float bf2f(__hip_bfloat16 x) { return __bfloat162float(x); }
static __device__ __forceinline__ __hip_bfloat16 f2bf(float x) { return __float2bfloat16(x); }
static __device__ __forceinline__ short f2bs(float x) {
  union { __hip_bfloat16 b; short s; } u; u.b = __float2bfloat16(x); return u.s;
}
static __device__ __forceinline__ float s2f(short v) {
  union { float f; unsigned u; } x; x.u = ((unsigned)(unsigned short)v) << 16; return x.f;
}
static __device__ __forceinline__ bf16x4 cvt4(float4 f) {
  bf16x4 r; r[0] = f2bs(f.x); r[1] = f2bs(f.y); r[2] = f2bs(f.z); r[3] = f2bs(f.w);
  return r;
}
static __device__ __forceinline__ bf16x8 ldg8(const __hip_bfloat16* p) {
  return *(const bf16x8*)p;
}
// async global->LDS, 16B per lane; LDS dest = wave-uniform base + lane*16
static __device__ __forceinline__ void gl_lds16(const __hip_bfloat16* g, __hip_bfloat16* l) {
  __builtin_amdgcn_global_load_lds(
      (const __attribute__((address_space(1))) void*)g,
      (__attribute__((address_space(3))) void*)l, 16, 0, 0);
}

// ---------------------------------------------------------------------------
// cvt: fp32 -> bf16, each element exactly once.  9 jobs.
// ---------------------------------------------------------------------------
struct CvtJob { const float* src; __hip_bfloat16* dst; int n4; };
struct CvtArgs { CvtJob j[9]; };

__global__ __launch_bounds__(256) void cvt_kernel(CvtArgs a) {
  const CvtJob jb = a.j[blockIdx.y];
  const float4* s = (const float4*)jb.src;
  bf16x4* d = (bf16x4*)jb.dst;
  const int stride = gridDim.x * 256;
  for (int i = blockIdx.x * 256 + threadIdx.x; i < jb.n4; i += stride)
    d[i] = cvt4(s[i]);
}

// ---------------------------------------------------------------------------
// proj (256^2, BK=64, 4-phase fine interleave, 2-slot dbuf = 128 KiB):
// C = (A@W^T + b)*osc.  8 waves (2Mx4N), per-wave 128x64, acc[8][4].
// Per tile: 4 phases (kh x mh); phase p issues ONE stage_half piece of tile
// t+1 (A-h0 | A-h1 | W-h0 | W-h1) so all 8 gloads are in flight 1-4 phases
// before the boundary.  Each phase: {ds_read 4-8 b128 | stage | s_barrier |
// lgkmcnt(0)+sched_barrier | setprio(1) 16 MFMA setprio(0) | s_barrier}.
// Boundary: per-wave vmcnt(0) (drains its own early-issued loads) + the
// phase-closing barrier publishes tile t+1.  XOR swizzle (0 conflicts).
// ---------------------------------------------------------------------------
struct Gemm { const __hip_bfloat16* A; const __hip_bfloat16* W;
              const float* bias; __hip_bfloat16* out; int mode; int mBits; int nBlk;
              float oscale; };
struct ProjArgs { Gemm g[5]; };

static __device__ __forceinline__ void stage_half(const __hip_bfloat16* gtile,
                                                  __hip_bfloat16* ltile,
                                                  int half, int wave, int lane) {
  const int r = lane >> 3;                 // 0..7
  const int chunk = (lane & 7) ^ r;        // pre-swizzled source chunk
#pragma unroll
  for (int c = 0; c < 2; c++) {
    const int rowbase = half * 128 + c * 64 + wave * 8;
    gl_lds16(gtile + (size_t)(rowbase + r) * 1024 + chunk * 8,
             ltile + (size_t)rowbase * 64);   // wave-uniform base + lane*16
  }
}

__global__ __launch_bounds__(512, 2) void proj_kernel(ProjArgs pa) {
  const Gemm g = pa.g[blockIdx.y];
  if ((int)blockIdx.x >= g.nBlk) return;
  __shared__ __hip_bfloat16 As[2][256][64];   // 64 KiB
  __shared__ __hip_bfloat16 Ws[2][256][64];   // 64 KiB

  const int bid = blockIdx.x;
  const int m0 = (bid & ((1 << g.mBits) - 1)) * 256;
  const int n0 = (bid >> g.mBits) * 256;
  const int tid = threadIdx.x;
  const int wave = tid >> 6, lane = tid & 63;
  const int q16 = lane >> 4, l16 = lane & 15;
  const int wr = wave >> 2, wc = wave & 3;     // 2 (M) x 4 (N) wave grid
  const int l7 = l16 & 7;

  const __hip_bfloat16* Ag = g.A + (size_t)m0 * 1024;
  const __hip_bfloat16* Wg = g.W + (size_t)n0 * 1024;

  f32x4 acc[8][4] = {};

  // prologue: stage tile 0 fully (8 gloads), drain, publish
  stage_half(Ag, &As[0][0][0], 0, wave, lane);
  stage_half(Ag, &As[0][0][0], 1, wave, lane);
  stage_half(Wg, &Ws[0][0][0], 0, wave, lane);
  stage_half(Wg, &Ws[0][0][0], 1, wave, lane);
  VMCNT0();
  BARX();

  for (int t = 0; t < 16; ++t) {
    const int sl = t & 1, sn = sl ^ 1;
    const __hip_bfloat16* Ac = &As[sl][0][0];
    const __hip_bfloat16* Wc = &Ws[sl][0][0];
    const bool pf = (t + 1 < 16);
    const __hip_bfloat16* gA1 = Ag + (size_t)(t + 1) * 64;
    const __hip_bfloat16* gW1 = Wg + (size_t)(t + 1) * 64;

    bf16x8 bw[4], af[4];
#pragma unroll
    for (int kh = 0; kh < 2; kh++) {
      const int csw = ((kh * 4 + q16) ^ l7) * 8;   // swizzled read column

      // ---- phase (kh, mh=0): 8 ds_read + stage piece ----
#pragma unroll
      for (int ni = 0; ni < 4; ni++)
        bw[ni] = *(const bf16x8*)(Wc + (size_t)(wc * 64 + ni * 16 + l16) * 64 + csw);
#pragma unroll
      for (int mi = 0; mi < 4; mi++)
        af[mi] = *(const bf16x8*)(Ac + (size_t)(wr * 128 + mi * 16 + l16) * 64 + csw);
      if (pf) {
        if (kh == 0) stage_half(gA1, &As[sn][0][0], 0, wave, lane);
        else         stage_half(gW1, &Ws[sn][0][0], 0, wave, lane);
      }
      BARX();
      LGKM0();
      __builtin_amdgcn_s_setprio(1);
#pragma unroll
      for (int ni = 0; ni < 4; ni++)
#pragma unroll
        for (int mi = 0; mi < 4; mi++)
          acc[mi][ni] = MFMA_BF16(af[mi], bw[ni], acc[mi][ni], 0, 0, 0);
      __builtin_amdgcn_s_setprio(0);
      BARX();

      // ---- phase (kh, mh=1): 4 ds_read + stage piece ----
#pragma unroll
      for (int mi = 0; mi < 4; mi++)
        af[mi] = *(const bf16x8*)(Ac + (size_t)(wr * 128 + 64 + mi * 16 + l16) * 64 + csw);
      if (pf) {
        if (kh == 0) stage_half(gA1, &As[sn][0][0], 1, wave, lane);
        else         stage_half(gW1, &Ws[sn][0][0], 1, wave, lane);
      }
      BARX();
      LGKM0();
      __builtin_amdgcn_s_setprio(1);
#pragma unroll
      for (int ni = 0; ni < 4; ni++)
#pragma unroll
        for (int mi = 0; mi < 4; mi++)
          acc[4 + mi][ni] = MFMA_BF16(af[mi], bw[ni], acc[4 + mi][ni], 0, 0, 0);
      __builtin_amdgcn_s_setprio(0);
      // tile boundary: drain this wave's early-issued loads, then publish
      if (kh == 1 && pf) VMCNT0();
      BARX();
    }
  }

#pragma unroll
  for (int ni = 0; ni < 4; ni++) {
    const int n = n0 + wc * 64 + ni * 16 + l16;
#pragma unroll
    for (int mi = 0; mi < 8; mi++) {
#pragma unroll
      for (int rr = 0; rr < 4; rr++) {
        const int m = m0 + wr * 128 + mi * 16 + q16 * 4 + rr;
        float val = acc[mi][ni][rr];
        size_t oidx;
        if (g.mode == 0) {
          val = (val + g.bias[n]) * g.oscale;
          const int b = m >> 9, s = m & 511;
          const int h = n >> 6, d = n & 63;
          oidx = ((size_t)((b * 16 + h) * 512 + s)) * 64 + d;
        } else if (g.mode == 1) {
          // operand-swapped V GEMM: m = hid (h,d), n = (b,s)
          val = (val + g.bias[m]) * g.oscale;
          const int b = n >> 9, s = n & 511;
          const int h = m >> 6, d = m & 63;
          oidx = ((size_t)((b * 16 + h) * 64 + d)) * 512 + s;
        } else {
          val = (val + g.bias[n]) * g.oscale;
          const int h = n >> 6, d = n & 63;
          oidx = ((size_t)(h * 512 + m)) * 64 + d;
        }
        g.out[oidx] = f2bf(val);
      }
    }
  }
}

// ---------------------------------------------------------------------------
// attn: fused online-softmax version (flash-style), 3 blocks/CU (round 5).
// ---------------------------------------------------------------------------
__global__ __launch_bounds__(256) void attn_kernel(
    const __hip_bfloat16* __restrict__ ql,   // [B*NH,512,64] (pre-scaled)
    const __hip_bfloat16* __restrict__ kl,   // [B*NH,512,64]
    const __hip_bfloat16* __restrict__ vlT,  // [B*NH,64,512]
    const __hip_bfloat16* __restrict__ pk,   // [NH,512,64]  (rows = jj = q-k)
    const __hip_bfloat16* __restrict__ pq,   // [NH,512,64]  (pre-scaled)
    float* __restrict__ out)                 // [B,S,HID] fp32
{
  __shared__ __align__(16) __hip_bfloat16 pool[2][64][72];  // kl rows 0-31, pk rows 32-63
  __shared__ __align__(16) __hip_bfloat16 pqs[2][32][72];   // pq windows
  __shared__ __align__(16) float qkbuf[32][36];             // qk term, f32
  __shared__ __align__(16) __hip_bfloat16 cpb[2][32][68];   // cp: [par][q][jj]
  __shared__ __align__(16) __hip_bfloat16 pT[64][36];       // p2c: [dlt+32][k]
  __shared__ __align__(16) __hip_bfloat16 ptile[32][40];    // P tile (MFMA-A layout)
  __shared__ __align__(16) __hip_bfloat16 vt[64][40];       // V^T tile [d][k]
  __shared__ float mred[32];
  __shared__ float rsum[32];
  // total 53,504 B -> 3 blocks/CU

  const int bid = blockIdx.x;
  const int qt = 15 - (bid >> 7);
  const int bh = bid & 127;
  const int h = bh & 15, b = bh >> 4;
  const int q0 = qt * 32;

  const __hip_bfloat16* qlp = ql + (size_t)bh * 512 * 64;
  const __hip_bfloat16* klp = kl + (size_t)bh * 512 * 64;
  const __hip_bfloat16* vtp = vlT + (size_t)bh * 64 * 512;
  const __hip_bfloat16* pkp = pk + (size_t)h * 512 * 64;
  const __hip_bfloat16* pqp = pq + (size_t)h * 512 * 64;

  const int tid = threadIdx.x, wave = tid >> 6, lane = tid & 63;
  const int q16 = lane >> 4, l16 = lane & 15;
  const int wr = wave & 1, wc = wave >> 1;   // PV wave grid

  // ql B-fragments (cols of the swapped score MFMAs), loop-invariant
  bf16x8 qlB[2][2];
#pragma unroll
  for (int ksi = 0; ksi < 2; ksi++)
#pragma unroll
    for (int bq = 0; bq < 2; bq++)
      qlB[ksi][bq] = ldg8(qlp + (size_t)(q0 + bq * 16 + l16) * 64 + ksi * 32 + q16 * 8);

  // zero pqs[1] (window "-1" for it=0; feeds pT rows 0..31, masked-only)
  {
    int4 z = {0, 0, 0, 0};
    *(int4*)(&pqs[1][tid >> 3][(tid & 7) * 8]) = z;
  }

  const int kEnd = q0 + 32;
  const int nIter = kEnd >> 5;

  const int sr = tid >> 3, sseg = tid & 7;
  const int vr = tid >> 2, vs = tid & 3;
  int4 rKv, rPKv, rPQv, rVt;
  {
    rKv  = ((const int4*)(klp + (size_t)(q0 + sr) * 64))[sseg];
    rPKv = ((const int4*)(pkp + (size_t)(0 + sr) * 64))[sseg];
    rPQv = ((const int4*)(pqp + (size_t)(0 + sr) * 64))[sseg];
    rVt  = ((const int4*)(vtp + (size_t)vr * 512 + q0))[vs];
  }

  const int aq = tid >> 3;           // assembly q-row (fixed per thread)
  const int kb = (tid & 7) * 4;      // assembly k-quad base
  float m_old = -INFINITY, s_part = 0.f;
  f32x4 octx[2] = {};

  for (int it = 0; it < nIter; ++it) {
    const int k0 = q0 - it * 32;
    const int par = it & 1;
    // --- region1: staging + global prefetch for it+1 ---
    *(int4*)(&pool[par][sr][sseg * 8])      = rKv;
    *(int4*)(&pool[par][32 + sr][sseg * 8]) = rPKv;
    *(int4*)(&pqs[par][sr][sseg * 8])       = rPQv;
    if (it + 1 < nIter) {
      const int k0n = k0 - 32, jbn = (it + 1) * 32;
      rKv  = ((const int4*)(klp + (size_t)(k0n + sr) * 64))[sseg];
      rPKv = ((const int4*)(pkp + (size_t)(jbn + sr) * 64))[sseg];
      rPQv = ((const int4*)(pqp + (size_t)(jbn + sr) * 64))[sseg];
    }
    __syncthreads();   // barA

    // --- region2: wave-specialized score MFMAs + C-writes ---
    const int arb = (wave == 1) ? 32 : 0;
    f32x4 a4[2][2] = {};
    __builtin_amdgcn_s_setprio(1);
#pragma unroll
    for (int ksi = 0; ksi < 2; ksi++) {
      const int ko = ksi * 32 + q16 * 8;
      bf16x8 Af0 = *(const bf16x8*)(&pool[par][arb + l16][ko]);
      bf16x8 Af1 = *(const bf16x8*)(&pool[par][arb + 16 + l16][ko]);
      bf16x8 Bf0, Bf1;
      if (wave < 2) {
        Bf0 = qlB[ksi][0];
        Bf1 = qlB[ksi][1];
      } else {
        const int ps = (wave == 2) ? (par ^ 1) : par;
        Bf0 = *(const bf16x8*)(&pqs[ps][l16][ko]);
        Bf1 = *(const bf16x8*)(&pqs[ps][16 + l16][ko]);
      }
      a4[0][0] = MFMA_BF16(Af0, Bf0, a4[0][0], 0, 0, 0);
      a4[0][1] = MFMA_BF16(Af0, Bf1, a4[0][1], 0, 0, 0);
      a4[1][0] = MFMA_BF16(Af1, Bf0, a4[1][0], 0, 0, 0);
      a4[1][1] = MFMA_BF16(Af1, Bf1, a4[1][1], 0, 0, 0);
    }
    __builtin_amdgcn_s_setprio(0);
    if (wave == 0) {
#pragma unroll
      for (int a = 0; a < 2; a++)
#pragma unroll
        for (int bq = 0; bq < 2; bq++)
          *(f32x4*)(&qkbuf[bq * 16 + l16][a * 16 + q16 * 4]) = a4[a][bq];
    } else if (wave == 1) {
#pragma unroll
      for (int a = 0; a < 2; a++)
#pragma unroll
        for (int bq = 0; bq < 2; bq++) {
          bf16x4 v;
#pragma unroll
          for (int r = 0; r < 4; r++) v[r] = f2bs(a4[a][bq][r]);
          const int q = bq * 16 + l16, jr = a * 16 + q16 * 4;
          *(bf16x4*)(&cpb[par][q][32 + jr]) = v;      // window it (hi)
          *(bf16x4*)(&cpb[par ^ 1][q][jr]) = v;       // dup -> lo of it+1
        }
    } else {
      const int rb = (wave == 3) ? 32 : 0;
#pragma unroll
      for (int a = 0; a < 2; a++)
#pragma unroll
        for (int bq = 0; bq < 2; bq++) {
          bf16x4 v;
#pragma unroll
          for (int r = 0; r < 4; r++) v[r] = f2bs(a4[a][bq][r]);
          *(bf16x4*)(&pT[rb + bq * 16 + l16][a * 16 + q16 * 4]) = v;
        }
    }
    __syncthreads();   // barB

    // --- region3: assembly in regs + online softmax + P/vt staging ---
    {
      const f32x4 qk4 = *(const f32x4*)(&qkbuf[aq][kb]);
      float v[4];
      float tmax = -INFINITY;
#pragma unroll
      for (int j = 0; j < 4; j++) {
        const int dlt = aq - (kb + j);
        v[j] = qk4[j] + bf2f(cpb[par][aq][dlt + 32]) + bf2f(pT[dlt + 32][kb + j]);
        if ((it == 0) && (dlt < 0)) v[j] = -INFINITY;   // causal mask
        else tmax = fmaxf(tmax, v[j]);
      }
      tmax = fmaxf(tmax, __shfl_xor(tmax, 1));
      tmax = fmaxf(tmax, __shfl_xor(tmax, 2));
      tmax = fmaxf(tmax, __shfl_xor(tmax, 4));
      const float m_new = fmaxf(m_old, tmax);
      const float f = __expf(m_old - m_new);   // 0 at it=0 (m_old=-inf)
      bf16x4 pv4;
      float psum = 0.f;
#pragma unroll
      for (int j = 0; j < 4; j++) {
        const float p = __expf(v[j] - m_new);  // masked -> exp(-inf)=0
        pv4[j] = f2bs(p);
        psum += p;
      }
      s_part = s_part * f + psum;
      m_old = m_new;
      *(bf16x4*)(&ptile[aq][kb]) = pv4;
      if ((tid & 7) == 0) mred[aq] = f;
    }
    {  // V^T tile staging (single-buffered; protected by barC..barB window)
      *(int4*)(&vt[vr][vs * 8]) = rVt;
      if (it + 1 < nIter)
        rVt = ((const int4*)(vtp + (size_t)vr * 512 + (k0 - 32)))[vs];
    }
    __syncthreads();   // barC

    // --- region4: PV with online rescale ---
    {
      float fr[4];
#pragma unroll
      for (int rr = 0; rr < 4; rr++) fr[rr] = mred[wr * 16 + q16 * 4 + rr];
      bf16x8 af = *(const bf16x8*)(&ptile[wr * 16 + l16][q16 * 8]);
      __builtin_amdgcn_s_setprio(1);
#pragma unroll
      for (int cs = 0; cs < 2; cs++) {
        bf16x8 bv = *(const bf16x8*)(&vt[wc * 32 + cs * 16 + l16][q16 * 8]);
        f32x4 c = octx[cs];
#pragma unroll
        for (int rr = 0; rr < 4; rr++) c[rr] *= fr[rr];
        octx[cs] = MFMA_BF16(af, bv, c, 0, 0, 0);
      }
      __builtin_amdgcn_s_setprio(0);
    }
  }

  // rowsum reduce (8 threads per row, consecutive lanes)
  {
    float s = s_part;
    s += __shfl_xor(s, 1);
    s += __shfl_xor(s, 2);
    s += __shfl_xor(s, 4);
    if ((tid & 7) == 0) rsum[aq] = s;
  }
  __syncthreads();

  for (int cs = 0; cs < 2; cs++) {
    const int d = wc * 32 + cs * 16 + l16;
    for (int rr = 0; rr < 4; rr++) {
      const int qh = wr * 16 + q16 * 4 + rr;
      const float val = octx[cs][rr] / rsum[qh];
      out[((size_t)(b * 512 + q0 + qh)) * 1024 + h * 64 + d] = val;
    }
  }
}

// ---------------------------------------------------------------------------
extern "C" void kernel_launch(void* const* d_in, const int* in_sizes, int n_in,
                              void* d_out, int out_size, void* d_ws, size_t ws_size,
                              hipStream_t stream) {
  const float* q   = (const float*)d_in[0];
  const float* k   = (const float*)d_in[1];
  const float* v   = (const float*)d_in[2];
  // d_in[3] = attention_mask: deterministic causal tril -> not read
  const float* Wq  = (const float*)d_in[4];
  const float* bq  = (const float*)d_in[5];
  const float* Wk  = (const float*)d_in[6];
  const float* bk  = (const float*)d_in[7];
  const float* Wv  = (const float*)d_in[8];
  const float* bv  = (const float*)d_in[9];
  const float* Wpk = (const float*)d_in[10];
  const float* bpk = (const float*)d_in[11];
  const float* Wpq = (const float*)d_in[12];
  const float* bpq = (const float*)d_in[13];
  const float* rel = (const float*)d_in[14];
  float* out = (float*)d_out;

  char* ws = (char*)d_ws;
  const size_t MB = 1u << 20;
  __hip_bfloat16* bqi  = (__hip_bfloat16*)(ws);
  __hip_bfloat16* bki  = (__hip_bfloat16*)(ws + 8 * MB);
  __hip_bfloat16* bvi  = (__hip_bfloat16*)(ws + 16 * MB);
  __hip_bfloat16* bWq  = (__hip_bfloat16*)(ws + 24 * MB);
  __hip_bfloat16* bWk  = (__hip_bfloat16*)(ws + 26 * MB);
  __hip_bfloat16* bWv  = (__hip_bfloat16*)(ws + 28 * MB);
  __hip_bfloat16* bWpk = (__hip_bfloat16*)(ws + 30 * MB);
  __hip_bfloat16* bWpq = (__hip_bfloat16*)(ws + 32 * MB);
  __hip_bfloat16* brel = (__hip_bfloat16*)(ws + 34 * MB);
  __hip_bfloat16* wql  = (__hip_bfloat16*)(ws + 35 * MB);
  __hip_bfloat16* wkl  = (__hip_bfloat16*)(ws + 43 * MB);
  __hip_bfloat16* wvlT = (__hip_bfloat16*)(ws + 51 * MB);
  __hip_bfloat16* wpk  = (__hip_bfloat16*)(ws + 59 * MB);
  __hip_bfloat16* wpq  = (__hip_bfloat16*)(ws + 60 * MB);

  CvtArgs ca;
  ca.j[0] = { q,   bqi,  4194304 / 4 };
  ca.j[1] = { k,   bki,  4194304 / 4 };
  ca.j[2] = { v,   bvi,  4194304 / 4 };
  ca.j[3] = { Wq,  bWq,  1048576 / 4 };
  ca.j[4] = { Wk,  bWk,  1048576 / 4 };
  ca.j[5] = { Wv,  bWv,  1048576 / 4 };
  ca.j[6] = { Wpk, bWpk, 1048576 / 4 };
  ca.j[7] = { Wpq, bWpq, 1048576 / 4 };
  ca.j[8] = { rel + (size_t)512 * 1024, brel, 524288 / 4 };
  cvt_kernel<<<dim3(1024, 9), 256, 0, stream>>>(ca);

  ProjArgs pj;
  pj.g[0] = { bqi,  bWq,  bq,  wql,  0, 4, 64, SCALE };  // Q pre-scaled
  pj.g[1] = { bki,  bWk,  bk,  wkl,  0, 4, 64, 1.0f };
  pj.g[2] = { bWv,  bvi,  bv,  wvlT, 1, 2, 64, 1.0f };   // operand-swapped V
  pj.g[3] = { brel, bWpk, bpk, wpk,  2, 1, 8,  1.0f };
  pj.g[4] = { brel, bWpq, bpq, wpq,  2, 1, 8,  SCALE };  // pq pre-scaled
  proj_kernel<<<dim3(64, 5), 512, 0, stream>>>(pj);

  attn_kernel<<<2048, 256, 0, stream>>>(wql, wkl, wvlT, wpk, wpq, out);
}

// Round 11
// 222.796 us; speedup vs baseline: 1.0923x; 1.0385x over previous
//
#include <hip/hip_runtime.h>
#include <hip/hip_bf16.h>
#include <math.h>

// B=8, S=512, HID=1024, NH=16, D=64, SPAN=512
// scale = 1/sqrt(64*3)  (pre-applied to Q and pq in proj epilogue)
#define SCALE 0.07216878364870323f
#define NEG_BIG -1e30f

typedef __attribute__((ext_vector_type(8))) short bf16x8;
typedef __attribute__((ext_vector_type(4))) short bf16x4;
typedef __attribute__((ext_vector_type(4))) float f32x4;
#define MFMA_BF16 __builtin_amdgcn_mfma_f32_16x16x32_bf16

static __device__ __forceinline__ float bf2f(__hip_bfloat16 x) { return __bfloat162float(x); }
static __device__ __forceinline__ __hip_bfloat16 f2bf(float x) { return __float2bfloat16(x); }
static __device__ __forceinline__ short f2bs(float x) {
  union { __hip_bfloat16 b; short s; } u; u.b = __float2bfloat16(x); return u.s;
}
static __device__ __forceinline__ float s2f(short v) {
  union { float f; unsigned u; } x; x.u = ((unsigned)(unsigned short)v) << 16; return x.f;
}
static __device__ __forceinline__ bf16x4 cvt4(float4 f) {
  bf16x4 r; r[0] = f2bs(f.x); r[1] = f2bs(f.y); r[2] = f2bs(f.z); r[3] = f2bs(f.w);
  return r;
}
static __device__ __forceinline__ bf16x8 ldg8(const __hip_bfloat16* p) {
  return *(const bf16x8*)p;
}
// async global->LDS, 16B per lane; LDS dest = wave-uniform base + lane*16
static __device__ __forceinline__ void gl_lds16(const __hip_bfloat16* g, __hip_bfloat16* l) {
  __builtin_amdgcn_global_load_lds(
      (const __attribute__((address_space(1))) void*)g,
      (__attribute__((address_space(3))) void*)l, 16, 0, 0);
}

// ---------------------------------------------------------------------------
// cvt: fp32 -> bf16, each element exactly once.  9 jobs.
// ---------------------------------------------------------------------------
struct CvtJob { const float* src; __hip_bfloat16* dst; int n4; };
struct CvtArgs { CvtJob j[9]; };

__global__ __launch_bounds__(256) void cvt_kernel(CvtArgs a) {
  const CvtJob jb = a.j[blockIdx.y];
  const float4* s = (const float4*)jb.src;
  bf16x4* d = (bf16x4*)jb.dst;
  const int stride = gridDim.x * 256;
  for (int i = blockIdx.x * 256 + threadIdx.x; i < jb.n4; i += stride)
    d[i] = cvt4(s[i]);
}

// ---------------------------------------------------------------------------
// proj (256x128 tile, BK=64, SINGLE-buffered 48 KiB LDS -> 2 blocks/CU):
// C = (A@W^T + b)*osc.  Residency fix: grid 448 working blocks (was 208);
// co-resident block hides the per-tile barrier drain (m97/m114 regime).
// 8 waves as 4M x 2N, per-wave 64x64, acc[4][4]; 32 MFMA + 16 ds_read/tile.
// XOR swizzle via pre-swizzled gload source (verified 0 conflicts).
// ---------------------------------------------------------------------------
struct Gemm { const __hip_bfloat16* A; const __hip_bfloat16* W;
              const float* bias; __hip_bfloat16* out; int mode; int mBits; int nBlk;
              float oscale; };
struct ProjArgs { Gemm g[5]; };

// stage nrows x 64 tile (row-major, ld=1024) into linear LDS; nrows/64 issues.
static __device__ __forceinline__ void stage_tile(const __hip_bfloat16* gtile,
                                                  __hip_bfloat16* ltile,
                                                  int nrows, int wave, int lane) {
  const int r = lane >> 3;                 // 0..7
  const int chunk = (lane & 7) ^ r;        // pre-swizzled source chunk
#pragma unroll
  for (int c = 0; c < 4; c++) {
    if (c * 64 >= nrows) break;
    const int rowbase = c * 64 + wave * 8;
    gl_lds16(gtile + (size_t)(rowbase + r) * 1024 + chunk * 8,
             ltile + (size_t)rowbase * 64);   // wave-uniform base + lane*16
  }
}

__global__ __launch_bounds__(512, 2) void proj_kernel(ProjArgs pa) {
  const Gemm g = pa.g[blockIdx.y];
  if ((int)blockIdx.x >= g.nBlk) return;
  __shared__ __hip_bfloat16 As[256][64];   // 32 KiB
  __shared__ __hip_bfloat16 Ws[128][64];   // 16 KiB

  const int bid = blockIdx.x;
  const int m0 = (bid & ((1 << g.mBits) - 1)) * 256;
  const int n0 = (bid >> g.mBits) * 128;
  const int tid = threadIdx.x;
  const int wave = tid >> 6, lane = tid & 63;
  const int q16 = lane >> 4, l16 = lane & 15;
  const int wr = wave >> 1, wc = wave & 1;     // 4 (M) x 2 (N) wave grid
  const int l7 = l16 & 7;

  const __hip_bfloat16* Ag = g.A + (size_t)m0 * 1024;
  const __hip_bfloat16* Wg = g.W + (size_t)n0 * 1024;

  f32x4 acc[4][4] = {};

  for (int t = 0; t < 16; ++t) {
    __syncthreads();   // previous tile's LDS reads complete
    stage_tile(Ag + t * 64, &As[0][0], 256, wave, lane);
    stage_tile(Wg + t * 64, &Ws[0][0], 128, wave, lane);
    __syncthreads();   // staging drained (vmcnt0+lgkm0) and visible
#pragma unroll
    for (int kh = 0; kh < 2; kh++) {
      const int csw = ((kh * 4 + q16) ^ l7) * 8;   // swizzled read column
      bf16x8 bw[4], af[4];
#pragma unroll
      for (int ni = 0; ni < 4; ni++)
        bw[ni] = *(const bf16x8*)(&Ws[wc * 64 + ni * 16 + l16][0] + csw);
#pragma unroll
      for (int mi = 0; mi < 4; mi++)
        af[mi] = *(const bf16x8*)(&As[wr * 64 + mi * 16 + l16][0] + csw);
      __builtin_amdgcn_s_setprio(1);
#pragma unroll
      for (int ni = 0; ni < 4; ni++)
#pragma unroll
        for (int mi = 0; mi < 4; mi++)
          acc[mi][ni] = MFMA_BF16(af[mi], bw[ni], acc[mi][ni], 0, 0, 0);
      __builtin_amdgcn_s_setprio(0);
    }
  }

#pragma unroll
  for (int ni = 0; ni < 4; ni++) {
    const int n = n0 + wc * 64 + ni * 16 + l16;
#pragma unroll
    for (int mi = 0; mi < 4; mi++) {
#pragma unroll
      for (int rr = 0; rr < 4; rr++) {
        const int m = m0 + wr * 64 + mi * 16 + q16 * 4 + rr;
        float val = acc[mi][ni][rr];
        size_t oidx;
        if (g.mode == 0) {
          val = (val + g.bias[n]) * g.oscale;
          const int b = m >> 9, s = m & 511;
          const int h = n >> 6, d = n & 63;
          oidx = ((size_t)((b * 16 + h) * 512 + s)) * 64 + d;
        } else if (g.mode == 1) {
          // operand-swapped V GEMM: m = hid (h,d), n = (b,s)
          val = (val + g.bias[m]) * g.oscale;
          const int b = n >> 9, s = n & 511;
          const int h = m >> 6, d = m & 63;
          oidx = ((size_t)((b * 16 + h) * 64 + d)) * 512 + s;
        } else {
          val = (val + g.bias[n]) * g.oscale;
          const int h = n >> 6, d = n & 63;
          oidx = ((size_t)(h * 512 + m)) * 64 + d;
        }
        g.out[oidx] = f2bf(val);
      }
    }
  }
}

// ---------------------------------------------------------------------------
// attn: fused online-softmax version (flash-style), 3 blocks/CU (round 5).
// ---------------------------------------------------------------------------
__global__ __launch_bounds__(256) void attn_kernel(
    const __hip_bfloat16* __restrict__ ql,   // [B*NH,512,64] (pre-scaled)
    const __hip_bfloat16* __restrict__ kl,   // [B*NH,512,64]
    const __hip_bfloat16* __restrict__ vlT,  // [B*NH,64,512]
    const __hip_bfloat16* __restrict__ pk,   // [NH,512,64]  (rows = jj = q-k)
    const __hip_bfloat16* __restrict__ pq,   // [NH,512,64]  (pre-scaled)
    float* __restrict__ out)                 // [B,S,HID] fp32
{
  __shared__ __align__(16) __hip_bfloat16 pool[2][64][72];  // kl rows 0-31, pk rows 32-63
  __shared__ __align__(16) __hip_bfloat16 pqs[2][32][72];   // pq windows
  __shared__ __align__(16) float qkbuf[32][36];             // qk term, f32
  __shared__ __align__(16) __hip_bfloat16 cpb[2][32][68];   // cp: [par][q][jj]
  __shared__ __align__(16) __hip_bfloat16 pT[64][36];       // p2c: [dlt+32][k]
  __shared__ __align__(16) __hip_bfloat16 ptile[32][40];    // P tile (MFMA-A layout)
  __shared__ __align__(16) __hip_bfloat16 vt[64][40];       // V^T tile [d][k]
  __shared__ float mred[32];
  __shared__ float rsum[32];
  // total 53,504 B -> 3 blocks/CU

  const int bid = blockIdx.x;
  const int qt = 15 - (bid >> 7);
  const int bh = bid & 127;
  const int h = bh & 15, b = bh >> 4;
  const int q0 = qt * 32;

  const __hip_bfloat16* qlp = ql + (size_t)bh * 512 * 64;
  const __hip_bfloat16* klp = kl + (size_t)bh * 512 * 64;
  const __hip_bfloat16* vtp = vlT + (size_t)bh * 64 * 512;
  const __hip_bfloat16* pkp = pk + (size_t)h * 512 * 64;
  const __hip_bfloat16* pqp = pq + (size_t)h * 512 * 64;

  const int tid = threadIdx.x, wave = tid >> 6, lane = tid & 63;
  const int q16 = lane >> 4, l16 = lane & 15;
  const int wr = wave & 1, wc = wave >> 1;   // PV wave grid

  // ql B-fragments (cols of the swapped score MFMAs), loop-invariant
  bf16x8 qlB[2][2];
#pragma unroll
  for (int ksi = 0; ksi < 2; ksi++)
#pragma unroll
    for (int bq = 0; bq < 2; bq++)
      qlB[ksi][bq] = ldg8(qlp + (size_t)(q0 + bq * 16 + l16) * 64 + ksi * 32 + q16 * 8);

  // zero pqs[1] (window "-1" for it=0; feeds pT rows 0..31, masked-only)
  {
    int4 z = {0, 0, 0, 0};
    *(int4*)(&pqs[1][tid >> 3][(tid & 7) * 8]) = z;
  }

  const int kEnd = q0 + 32;
  const int nIter = kEnd >> 5;

  const int sr = tid >> 3, sseg = tid & 7;
  const int vr = tid >> 2, vs = tid & 3;
  int4 rKv, rPKv, rPQv, rVt;
  {
    rKv  = ((const int4*)(klp + (size_t)(q0 + sr) * 64))[sseg];
    rPKv = ((const int4*)(pkp + (size_t)(0 + sr) * 64))[sseg];
    rPQv = ((const int4*)(pqp + (size_t)(0 + sr) * 64))[sseg];
    rVt  = ((const int4*)(vtp + (size_t)vr * 512 + q0))[vs];
  }

  const int aq = tid >> 3;           // assembly q-row (fixed per thread)
  const int kb = (tid & 7) * 4;      // assembly k-quad base
  float m_old = -INFINITY, s_part = 0.f;
  f32x4 octx[2] = {};

  for (int it = 0; it < nIter; ++it) {
    const int k0 = q0 - it * 32;
    const int par = it & 1;
    // --- region1: staging + global prefetch for it+1 ---
    *(int4*)(&pool[par][sr][sseg * 8])      = rKv;
    *(int4*)(&pool[par][32 + sr][sseg * 8]) = rPKv;
    *(int4*)(&pqs[par][sr][sseg * 8])       = rPQv;
    if (it + 1 < nIter) {
      const int k0n = k0 - 32, jbn = (it + 1) * 32;
      rKv  = ((const int4*)(klp + (size_t)(k0n + sr) * 64))[sseg];
      rPKv = ((const int4*)(pkp + (size_t)(jbn + sr) * 64))[sseg];
      rPQv = ((const int4*)(pqp + (size_t)(jbn + sr) * 64))[sseg];
    }
    __syncthreads();   // barA

    // --- region2: wave-specialized score MFMAs + C-writes ---
    const int arb = (wave == 1) ? 32 : 0;
    f32x4 a4[2][2] = {};
    __builtin_amdgcn_s_setprio(1);
#pragma unroll
    for (int ksi = 0; ksi < 2; ksi++) {
      const int ko = ksi * 32 + q16 * 8;
      bf16x8 Af0 = *(const bf16x8*)(&pool[par][arb + l16][ko]);
      bf16x8 Af1 = *(const bf16x8*)(&pool[par][arb + 16 + l16][ko]);
      bf16x8 Bf0, Bf1;
      if (wave < 2) {
        Bf0 = qlB[ksi][0];
        Bf1 = qlB[ksi][1];
      } else {
        const int ps = (wave == 2) ? (par ^ 1) : par;
        Bf0 = *(const bf16x8*)(&pqs[ps][l16][ko]);
        Bf1 = *(const bf16x8*)(&pqs[ps][16 + l16][ko]);
      }
      a4[0][0] = MFMA_BF16(Af0, Bf0, a4[0][0], 0, 0, 0);
      a4[0][1] = MFMA_BF16(Af0, Bf1, a4[0][1], 0, 0, 0);
      a4[1][0] = MFMA_BF16(Af1, Bf0, a4[1][0], 0, 0, 0);
      a4[1][1] = MFMA_BF16(Af1, Bf1, a4[1][1], 0, 0, 0);
    }
    __builtin_amdgcn_s_setprio(0);
    if (wave == 0) {
#pragma unroll
      for (int a = 0; a < 2; a++)
#pragma unroll
        for (int bq = 0; bq < 2; bq++)
          *(f32x4*)(&qkbuf[bq * 16 + l16][a * 16 + q16 * 4]) = a4[a][bq];
    } else if (wave == 1) {
#pragma unroll
      for (int a = 0; a < 2; a++)
#pragma unroll
        for (int bq = 0; bq < 2; bq++) {
          bf16x4 v;
#pragma unroll
          for (int r = 0; r < 4; r++) v[r] = f2bs(a4[a][bq][r]);
          const int q = bq * 16 + l16, jr = a * 16 + q16 * 4;
          *(bf16x4*)(&cpb[par][q][32 + jr]) = v;      // window it (hi)
          *(bf16x4*)(&cpb[par ^ 1][q][jr]) = v;       // dup -> lo of it+1
        }
    } else {
      const int rb = (wave == 3) ? 32 : 0;
#pragma unroll
      for (int a = 0; a < 2; a++)
#pragma unroll
        for (int bq = 0; bq < 2; bq++) {
          bf16x4 v;
#pragma unroll
          for (int r = 0; r < 4; r++) v[r] = f2bs(a4[a][bq][r]);
          *(bf16x4*)(&pT[rb + bq * 16 + l16][a * 16 + q16 * 4]) = v;
        }
    }
    __syncthreads();   // barB

    // --- region3: assembly in regs + online softmax + P/vt staging ---
    {
      const f32x4 qk4 = *(const f32x4*)(&qkbuf[aq][kb]);
      float v[4];
      float tmax = -INFINITY;
#pragma unroll
      for (int j = 0; j < 4; j++) {
        const int dlt = aq - (kb + j);
        v[j] = qk4[j] + bf2f(cpb[par][aq][dlt + 32]) + bf2f(pT[dlt + 32][kb + j]);
        if ((it == 0) && (dlt < 0)) v[j] = -INFINITY;   // causal mask
        else tmax = fmaxf(tmax, v[j]);
      }
      tmax = fmaxf(tmax, __shfl_xor(tmax, 1));
      tmax = fmaxf(tmax, __shfl_xor(tmax, 2));
      tmax = fmaxf(tmax, __shfl_xor(tmax, 4));
      const float m_new = fmaxf(m_old, tmax);
      const float f = __expf(m_old - m_new);   // 0 at it=0 (m_old=-inf)
      bf16x4 pv4;
      float psum = 0.f;
#pragma unroll
      for (int j = 0; j < 4; j++) {
        const float p = __expf(v[j] - m_new);  // masked -> exp(-inf)=0
        pv4[j] = f2bs(p);
        psum += p;
      }
      s_part = s_part * f + psum;
      m_old = m_new;
      *(bf16x4*)(&ptile[aq][kb]) = pv4;
      if ((tid & 7) == 0) mred[aq] = f;
    }
    {  // V^T tile staging (single-buffered; protected by barC..barB window)
      *(int4*)(&vt[vr][vs * 8]) = rVt;
      if (it + 1 < nIter)
        rVt = ((const int4*)(vtp + (size_t)vr * 512 + (k0 - 32)))[vs];
    }
    __syncthreads();   // barC

    // --- region4: PV with online rescale ---
    {
      float fr[4];
#pragma unroll
      for (int rr = 0; rr < 4; rr++) fr[rr] = mred[wr * 16 + q16 * 4 + rr];
      bf16x8 af = *(const bf16x8*)(&ptile[wr * 16 + l16][q16 * 8]);
      __builtin_amdgcn_s_setprio(1);
#pragma unroll
      for (int cs = 0; cs < 2; cs++) {
        bf16x8 bv = *(const bf16x8*)(&vt[wc * 32 + cs * 16 + l16][q16 * 8]);
        f32x4 c = octx[cs];
#pragma unroll
        for (int rr = 0; rr < 4; rr++) c[rr] *= fr[rr];
        octx[cs] = MFMA_BF16(af, bv, c, 0, 0, 0);
      }
      __builtin_amdgcn_s_setprio(0);
    }
  }

  // rowsum reduce (8 threads per row, consecutive lanes)
  {
    float s = s_part;
    s += __shfl_xor(s, 1);
    s += __shfl_xor(s, 2);
    s += __shfl_xor(s, 4);
    if ((tid & 7) == 0) rsum[aq] = s;
  }
  __syncthreads();

  for (int cs = 0; cs < 2; cs++) {
    const int d = wc * 32 + cs * 16 + l16;
    for (int rr = 0; rr < 4; rr++) {
      const int qh = wr * 16 + q16 * 4 + rr;
      const float val = octx[cs][rr] / rsum[qh];
      out[((size_t)(b * 512 + q0 + qh)) * 1024 + h * 64 + d] = val;
    }
  }
}

// ---------------------------------------------------------------------------
extern "C" void kernel_launch(void* const* d_in, const int* in_sizes, int n_in,
                              void* d_out, int out_size, void* d_ws, size_t ws_size,
                              hipStream_t stream) {
  const float* q   = (const float*)d_in[0];
  const float* k   = (const float*)d_in[1];
  const float* v   = (const float*)d_in[2];
  // d_in[3] = attention_mask: deterministic causal tril -> not read
  const float* Wq  = (const float*)d_in[4];
  const float* bq  = (const float*)d_in[5];
  const float* Wk  = (const float*)d_in[6];
  const float* bk  = (const float*)d_in[7];
  const float* Wv  = (const float*)d_in[8];
  const float* bv  = (const float*)d_in[9];
  const float* Wpk = (const float*)d_in[10];
  const float* bpk = (const float*)d_in[11];
  const float* Wpq = (const float*)d_in[12];
  const float* bpq = (const float*)d_in[13];
  const float* rel = (const float*)d_in[14];
  float* out = (float*)d_out;

  char* ws = (char*)d_ws;
  const size_t MB = 1u << 20;
  __hip_bfloat16* bqi  = (__hip_bfloat16*)(ws);
  __hip_bfloat16* bki  = (__hip_bfloat16*)(ws + 8 * MB);
  __hip_bfloat16* bvi  = (__hip_bfloat16*)(ws + 16 * MB);
  __hip_bfloat16* bWq  = (__hip_bfloat16*)(ws + 24 * MB);
  __hip_bfloat16* bWk  = (__hip_bfloat16*)(ws + 26 * MB);
  __hip_bfloat16* bWv  = (__hip_bfloat16*)(ws + 28 * MB);
  __hip_bfloat16* bWpk = (__hip_bfloat16*)(ws + 30 * MB);
  __hip_bfloat16* bWpq = (__hip_bfloat16*)(ws + 32 * MB);
  __hip_bfloat16* brel = (__hip_bfloat16*)(ws + 34 * MB);
  __hip_bfloat16* wql  = (__hip_bfloat16*)(ws + 35 * MB);
  __hip_bfloat16* wkl  = (__hip_bfloat16*)(ws + 43 * MB);
  __hip_bfloat16* wvlT = (__hip_bfloat16*)(ws + 51 * MB);
  __hip_bfloat16* wpk  = (__hip_bfloat16*)(ws + 59 * MB);
  __hip_bfloat16* wpq  = (__hip_bfloat16*)(ws + 60 * MB);

  CvtArgs ca;
  ca.j[0] = { q,   bqi,  4194304 / 4 };
  ca.j[1] = { k,   bki,  4194304 / 4 };
  ca.j[2] = { v,   bvi,  4194304 / 4 };
  ca.j[3] = { Wq,  bWq,  1048576 / 4 };
  ca.j[4] = { Wk,  bWk,  1048576 / 4 };
  ca.j[5] = { Wv,  bWv,  1048576 / 4 };
  ca.j[6] = { Wpk, bWpk, 1048576 / 4 };
  ca.j[7] = { Wpq, bWpq, 1048576 / 4 };
  ca.j[8] = { rel + (size_t)512 * 1024, brel, 524288 / 4 };
  cvt_kernel<<<dim3(1024, 9), 256, 0, stream>>>(ca);

  ProjArgs pj;
  // 256x128 tiles: nBlk = (M/256) * (N/128), mBits = log2(M/256)
  // brel is 512 rows -> rel jobs: mBits=1, nBlk = 2*8 = 16  (R10 bug: was 2/32)
  pj.g[0] = { bqi,  bWq,  bq,  wql,  0, 4, 128, SCALE };  // Q pre-scaled
  pj.g[1] = { bki,  bWk,  bk,  wkl,  0, 4, 128, 1.0f };
  pj.g[2] = { bWv,  bvi,  bv,  wvlT, 1, 2, 128, 1.0f };   // operand-swapped V (M=1024, N=4096)
  pj.g[3] = { brel, bWpk, bpk, wpk,  2, 1, 16,  1.0f };
  pj.g[4] = { brel, bWpq, bpq, wpq,  2, 1, 16,  SCALE };  // pq pre-scaled
  proj_kernel<<<dim3(128, 5), 512, 0, stream>>>(pj);

  attn_kernel<<<2048, 256, 0, stream>>>(wql, wkl, wvlT, wpk, wpq, out);
}

// Round 12
// 217.508 us; speedup vs baseline: 1.1189x; 1.0243x over previous
//
#include <hip/hip_runtime.h>
#include <hip/hip_bf16.h>
#include <math.h>

// B=8, S=512, HID=1024, NH=16, D=64, SPAN=512
// scale = 1/sqrt(64*3)  (pre-applied to Q and pq in proj epilogue)
#define SCALE 0.07216878364870323f
#define NEG_BIG -1e30f

typedef __attribute__((ext_vector_type(8))) short bf16x8;
typedef __attribute__((ext_vector_type(4))) short bf16x4;
typedef __attribute__((ext_vector_type(4))) float f32x4;
#define MFMA_BF16 __builtin_amdgcn_mfma_f32_16x16x32_bf16

static __device__ __forceinline__ float bf2f(__hip_bfloat16 x) { return __bfloat162float(x); }
static __device__ __forceinline__ __hip_bfloat16 f2bf(float x) { return __float2bfloat16(x); }
static __device__ __forceinline__ short f2bs(float x) {
  union { __hip_bfloat16 b; short s; } u; u.b = __float2bfloat16(x); return u.s;
}
static __device__ __forceinline__ float s2f(short v) {
  union { float f; unsigned u; } x; x.u = ((unsigned)(unsigned short)v) << 16; return x.f;
}
static __device__ __forceinline__ bf16x4 cvt4(float4 f) {
  bf16x4 r; r[0] = f2bs(f.x); r[1] = f2bs(f.y); r[2] = f2bs(f.z); r[3] = f2bs(f.w);
  return r;
}
static __device__ __forceinline__ bf16x8 ldg8(const __hip_bfloat16* p) {
  return *(const bf16x8*)p;
}
// async global->LDS, 16B per lane; LDS dest = wave-uniform base + lane*16
static __device__ __forceinline__ void gl_lds16(const __hip_bfloat16* g, __hip_bfloat16* l) {
  __builtin_amdgcn_global_load_lds(
      (const __attribute__((address_space(1))) void*)g,
      (__attribute__((address_space(3))) void*)l, 16, 0, 0);
}

// ---------------------------------------------------------------------------
// cvt: fp32 -> bf16, each element exactly once.  9 jobs.
// ---------------------------------------------------------------------------
struct CvtJob { const float* src; __hip_bfloat16* dst; int n4; };
struct CvtArgs { CvtJob j[9]; };

__global__ __launch_bounds__(256) void cvt_kernel(CvtArgs a) {
  const CvtJob jb = a.j[blockIdx.y];
  const float4* s = (const float4*)jb.src;
  bf16x4* d = (bf16x4*)jb.dst;
  const int stride = gridDim.x * 256;
  for (int i = blockIdx.x * 256 + threadIdx.x; i < jb.n4; i += stride)
    d[i] = cvt4(s[i]);
}

// ---------------------------------------------------------------------------
// proj (256x128 tile, BK=64, single-buffered 48 KiB LDS -> 2 blocks/CU):
// unchanged from round 11 (left the top-5 at <52 us).
// ---------------------------------------------------------------------------
struct Gemm { const __hip_bfloat16* A; const __hip_bfloat16* W;
              const float* bias; __hip_bfloat16* out; int mode; int mBits; int nBlk;
              float oscale; };
struct ProjArgs { Gemm g[5]; };

static __device__ __forceinline__ void stage_tile(const __hip_bfloat16* gtile,
                                                  __hip_bfloat16* ltile,
                                                  int nrows, int wave, int lane) {
  const int r = lane >> 3;                 // 0..7
  const int chunk = (lane & 7) ^ r;        // pre-swizzled source chunk
#pragma unroll
  for (int c = 0; c < 4; c++) {
    if (c * 64 >= nrows) break;
    const int rowbase = c * 64 + wave * 8;
    gl_lds16(gtile + (size_t)(rowbase + r) * 1024 + chunk * 8,
             ltile + (size_t)rowbase * 64);   // wave-uniform base + lane*16
  }
}

__global__ __launch_bounds__(512, 2) void proj_kernel(ProjArgs pa) {
  const Gemm g = pa.g[blockIdx.y];
  if ((int)blockIdx.x >= g.nBlk) return;
  __shared__ __hip_bfloat16 As[256][64];   // 32 KiB
  __shared__ __hip_bfloat16 Ws[128][64];   // 16 KiB

  const int bid = blockIdx.x;
  const int m0 = (bid & ((1 << g.mBits) - 1)) * 256;
  const int n0 = (bid >> g.mBits) * 128;
  const int tid = threadIdx.x;
  const int wave = tid >> 6, lane = tid & 63;
  const int q16 = lane >> 4, l16 = lane & 15;
  const int wr = wave >> 1, wc = wave & 1;     // 4 (M) x 2 (N) wave grid
  const int l7 = l16 & 7;

  const __hip_bfloat16* Ag = g.A + (size_t)m0 * 1024;
  const __hip_bfloat16* Wg = g.W + (size_t)n0 * 1024;

  f32x4 acc[4][4] = {};

  for (int t = 0; t < 16; ++t) {
    __syncthreads();   // previous tile's LDS reads complete
    stage_tile(Ag + t * 64, &As[0][0], 256, wave, lane);
    stage_tile(Wg + t * 64, &Ws[0][0], 128, wave, lane);
    __syncthreads();   // staging drained (vmcnt0+lgkm0) and visible
#pragma unroll
    for (int kh = 0; kh < 2; kh++) {
      const int csw = ((kh * 4 + q16) ^ l7) * 8;   // swizzled read column
      bf16x8 bw[4], af[4];
#pragma unroll
      for (int ni = 0; ni < 4; ni++)
        bw[ni] = *(const bf16x8*)(&Ws[wc * 64 + ni * 16 + l16][0] + csw);
#pragma unroll
      for (int mi = 0; mi < 4; mi++)
        af[mi] = *(const bf16x8*)(&As[wr * 64 + mi * 16 + l16][0] + csw);
      __builtin_amdgcn_s_setprio(1);
#pragma unroll
      for (int ni = 0; ni < 4; ni++)
#pragma unroll
        for (int mi = 0; mi < 4; mi++)
          acc[mi][ni] = MFMA_BF16(af[mi], bw[ni], acc[mi][ni], 0, 0, 0);
      __builtin_amdgcn_s_setprio(0);
    }
  }

#pragma unroll
  for (int ni = 0; ni < 4; ni++) {
    const int n = n0 + wc * 64 + ni * 16 + l16;
#pragma unroll
    for (int mi = 0; mi < 4; mi++) {
#pragma unroll
      for (int rr = 0; rr < 4; rr++) {
        const int m = m0 + wr * 64 + mi * 16 + q16 * 4 + rr;
        float val = acc[mi][ni][rr];
        size_t oidx;
        if (g.mode == 0) {
          val = (val + g.bias[n]) * g.oscale;
          const int b = m >> 9, s = m & 511;
          const int h = n >> 6, d = n & 63;
          oidx = ((size_t)((b * 16 + h) * 512 + s)) * 64 + d;
        } else if (g.mode == 1) {
          // operand-swapped V GEMM: m = hid (h,d), n = (b,s)
          val = (val + g.bias[m]) * g.oscale;
          const int b = n >> 9, s = n & 511;
          const int h = m >> 6, d = m & 63;
          oidx = ((size_t)((b * 16 + h) * 64 + d)) * 512 + s;
        } else {
          val = (val + g.bias[n]) * g.oscale;
          const int h = n >> 6, d = n & 63;
          oidx = ((size_t)(h * 512 + m)) * 64 + d;
        }
        g.out[oidx] = f2bf(val);
      }
    }
  }
}

// ---------------------------------------------------------------------------
// attn: flash-style, 2 barriers/iter, pre-sheared cp/p2c stores.
// Per iteration it (k-tile par = it&1):
//  regionA (after barC(it-1)): PV(it-1) + wave-specialized score MFMAs(it) +
//    C-writes: qkbuf (wave0, f32 b128); cpexp SPLIT single-write (wave1:
//    jr<=q -> cpexp[par][q][q-jr], else cpexp[par^1][q][q+32-jr]);
//    pTexp[q=k+jj-32][k] predicated single-write (waves 2/3).  | barB
//  regionB: assembly = 3 VECTOR reads (qkbuf b128 + cpexp b64 + pTexp b64),
//    online softmax in regs -> ptile/mred; vt stage; K/pk/pq stage for it+1;
//    global prefetch for it+2.                                 | barC
// Race audit: every producer->consumer pair separated by >=1 barrier
// (pqs[par^1]: read regionA(it), rewritten regionB(it) -- barB between).
// LDS 47,104 B -> 3 blocks/CU.
// ---------------------------------------------------------------------------
__global__ __launch_bounds__(256) void attn_kernel(
    const __hip_bfloat16* __restrict__ ql,   // [B*NH,512,64] (pre-scaled)
    const __hip_bfloat16* __restrict__ kl,   // [B*NH,512,64]
    const __hip_bfloat16* __restrict__ vlT,  // [B*NH,64,512]
    const __hip_bfloat16* __restrict__ pk,   // [NH,512,64]  (rows = jj = q-k)
    const __hip_bfloat16* __restrict__ pq,   // [NH,512,64]  (pre-scaled)
    float* __restrict__ out)                 // [B,S,HID] fp32
{
  __shared__ __align__(16) __hip_bfloat16 pool[2][64][72];   // 18,432
  __shared__ __align__(16) __hip_bfloat16 pqs[2][32][72];    //  9,216
  __shared__ __align__(16) float qkbuf[32][36];              //  4,608
  __shared__ __align__(16) __hip_bfloat16 cpexp[2][32][36];  //  4,608
  __shared__ __align__(16) __hip_bfloat16 pTexp[32][36];     //  2,304
  __shared__ __align__(16) __hip_bfloat16 ptile[32][40];     //  2,560
  __shared__ __align__(16) __hip_bfloat16 vt[64][40];        //  5,120
  __shared__ float mred[32];                                 //    128
  __shared__ float rsum[32];                                 //    128
  // total 47,104 B -> 3 blocks/CU

  const int bid = blockIdx.x;
  const int qt = 15 - (bid >> 7);
  const int bh = bid & 127;
  const int h = bh & 15, b = bh >> 4;
  const int q0 = qt * 32;

  const __hip_bfloat16* qlp = ql + (size_t)bh * 512 * 64;
  const __hip_bfloat16* klp = kl + (size_t)bh * 512 * 64;
  const __hip_bfloat16* vtp = vlT + (size_t)bh * 64 * 512;
  const __hip_bfloat16* pkp = pk + (size_t)h * 512 * 64;
  const __hip_bfloat16* pqp = pq + (size_t)h * 512 * 64;

  const int tid = threadIdx.x, wave = tid >> 6, lane = tid & 63;
  const int q16 = lane >> 4, l16 = lane & 15;
  const int wr = wave & 1, wc = wave >> 1;   // PV wave grid

  // ql B-fragments (cols of the swapped score MFMAs), loop-invariant
  bf16x8 qlB[2][2];
#pragma unroll
  for (int ksi = 0; ksi < 2; ksi++)
#pragma unroll
    for (int bq = 0; bq < 2; bq++)
      qlB[ksi][bq] = ldg8(qlp + (size_t)(q0 + bq * 16 + l16) * 64 + ksi * 32 + q16 * 8);

  const int kEnd = q0 + 32;
  const int nIter = kEnd >> 5;

  const int sr = tid >> 3, sseg = tid & 7;
  const int vr = tid >> 2, vs = tid & 3;
  int4 rKv, rPKv, rPQv, rVt;
  {
    rKv  = ((const int4*)(klp + (size_t)(q0 + sr) * 64))[sseg];
    rPKv = ((const int4*)(pkp + (size_t)(0 + sr) * 64))[sseg];
    rPQv = ((const int4*)(pqp + (size_t)(0 + sr) * 64))[sseg];
    rVt  = ((const int4*)(vtp + (size_t)vr * 512 + q0))[vs];
  }

  // prologue: zero pqs[1] (window "-1"), stage tile 0, prefetch tile 1 regs
  {
    int4 z = {0, 0, 0, 0};
    *(int4*)(&pqs[1][sr][sseg * 8]) = z;
    *(int4*)(&pool[0][sr][sseg * 8])      = rKv;
    *(int4*)(&pool[0][32 + sr][sseg * 8]) = rPKv;
    *(int4*)(&pqs[0][sr][sseg * 8])       = rPQv;
    if (1 < nIter) {
      rKv  = ((const int4*)(klp + (size_t)(q0 - 32 + sr) * 64))[sseg];
      rPKv = ((const int4*)(pkp + (size_t)(32 + sr) * 64))[sseg];
      rPQv = ((const int4*)(pqp + (size_t)(32 + sr) * 64))[sseg];
    }
  }
  __syncthreads();

  const int aq = tid >> 3;           // assembly q-row (fixed per thread)
  const int kb = (tid & 7) * 4;      // assembly k-quad base
  float m_old = -INFINITY, s_part = 0.f;
  f32x4 octx[2] = {};

  for (int it = 0; it < nIter; ++it) {
    const int k0 = q0 - it * 32;
    const int par = it & 1;

    // ===== regionA: PV(it-1) + score MFMAs(it) + C-writes =====
    if (it > 0) {
      float fr[4];
#pragma unroll
      for (int rr = 0; rr < 4; rr++) fr[rr] = mred[wr * 16 + q16 * 4 + rr];
      bf16x8 af = *(const bf16x8*)(&ptile[wr * 16 + l16][q16 * 8]);
#pragma unroll
      for (int cs = 0; cs < 2; cs++) {
        bf16x8 bv = *(const bf16x8*)(&vt[wc * 32 + cs * 16 + l16][q16 * 8]);
        f32x4 c = octx[cs];
#pragma unroll
        for (int rr = 0; rr < 4; rr++) c[rr] *= fr[rr];
        octx[cs] = MFMA_BF16(af, bv, c, 0, 0, 0);
      }
    }
    {
      const int arb = (wave == 1) ? 32 : 0;
      f32x4 a4[2][2] = {};
      __builtin_amdgcn_s_setprio(1);
#pragma unroll
      for (int ksi = 0; ksi < 2; ksi++) {
        const int ko = ksi * 32 + q16 * 8;
        bf16x8 Af0 = *(const bf16x8*)(&pool[par][arb + l16][ko]);
        bf16x8 Af1 = *(const bf16x8*)(&pool[par][arb + 16 + l16][ko]);
        bf16x8 Bf0, Bf1;
        if (wave < 2) {
          Bf0 = qlB[ksi][0];
          Bf1 = qlB[ksi][1];
        } else {
          const int ps = (wave == 2) ? (par ^ 1) : par;
          Bf0 = *(const bf16x8*)(&pqs[ps][l16][ko]);
          Bf1 = *(const bf16x8*)(&pqs[ps][16 + l16][ko]);
        }
        a4[0][0] = MFMA_BF16(Af0, Bf0, a4[0][0], 0, 0, 0);
        a4[0][1] = MFMA_BF16(Af0, Bf1, a4[0][1], 0, 0, 0);
        a4[1][0] = MFMA_BF16(Af1, Bf0, a4[1][0], 0, 0, 0);
        a4[1][1] = MFMA_BF16(Af1, Bf1, a4[1][1], 0, 0, 0);
      }
      __builtin_amdgcn_s_setprio(0);
      if (wave == 0) {
#pragma unroll
        for (int a = 0; a < 2; a++)
#pragma unroll
          for (int bq = 0; bq < 2; bq++)
            *(f32x4*)(&qkbuf[bq * 16 + l16][a * 16 + q16 * 4]) = a4[a][bq];
      } else if (wave == 1) {
        // cp value (q, jr) -> single write: tile it at kl=q-jr (jr<=q),
        // else tile it+1 at kl=q+32-jr
#pragma unroll
        for (int a = 0; a < 2; a++)
#pragma unroll
          for (int bq = 0; bq < 2; bq++) {
            const int q = bq * 16 + l16;
#pragma unroll
            for (int r = 0; r < 4; r++) {
              const int jr = a * 16 + q16 * 4 + r;
              const short val = f2bs(a4[a][bq][r]);
              if (jr <= q) ((short*)&cpexp[par][q][0])[q - jr] = val;
              else         ((short*)&cpexp[par ^ 1][q][0])[q + 32 - jr] = val;
            }
          }
      } else {
        // p2c value (jj_abs, k) -> pTexp[q=k+jj_abs-32][k] when q in [0,32)
        const int jjb = (wave == 3) ? 32 : 0;
#pragma unroll
        for (int a = 0; a < 2; a++)
#pragma unroll
          for (int bq = 0; bq < 2; bq++) {
            const int jj = jjb + bq * 16 + l16;
#pragma unroll
            for (int r = 0; r < 4; r++) {
              const int k = a * 16 + q16 * 4 + r;
              const int q = k + jj - 32;
              if (q >= 0 && q < 32)
                ((short*)&pTexp[q][0])[k] = f2bs(a4[a][bq][r]);
            }
          }
      }
    }
    __syncthreads();   // barB

    // ===== regionB: assembly + online softmax + vt/K/pk/pq staging =====
    {
      const f32x4 qk4 = *(const f32x4*)(&qkbuf[aq][kb]);
      const bf16x4 cp4 = *(const bf16x4*)(&cpexp[par][aq][kb]);
      const bf16x4 p4  = *(const bf16x4*)(&pTexp[aq][kb]);
      float v[4];
      float tmax = -INFINITY;
#pragma unroll
      for (int j = 0; j < 4; j++) {
        v[j] = qk4[j] + s2f(cp4[j]) + s2f(p4[j]);
        const bool msk = (it == 0) && (aq < kb + j);
        if (msk) v[j] = -INFINITY;   // causal mask (garbage cp read discarded)
        else tmax = fmaxf(tmax, v[j]);
      }
      tmax = fmaxf(tmax, __shfl_xor(tmax, 1));
      tmax = fmaxf(tmax, __shfl_xor(tmax, 2));
      tmax = fmaxf(tmax, __shfl_xor(tmax, 4));
      const float m_new = fmaxf(m_old, tmax);
      const float f = __expf(m_old - m_new);   // 0 at it=0 (m_old=-inf)
      bf16x4 pv4;
      float psum = 0.f;
#pragma unroll
      for (int j = 0; j < 4; j++) {
        const float p = __expf(v[j] - m_new);  // masked -> exp(-inf)=0
        pv4[j] = f2bs(p);
        psum += p;
      }
      s_part = s_part * f + psum;
      m_old = m_new;
      *(bf16x4*)(&ptile[aq][kb]) = pv4;
      if ((tid & 7) == 0) mred[aq] = f;
    }
    {  // vt(it) stage + prefetch
      *(int4*)(&vt[vr][vs * 8]) = rVt;
      if (it + 1 < nIter)
        rVt = ((const int4*)(vtp + (size_t)vr * 512 + (k0 - 32)))[vs];
    }
    if (it + 1 < nIter) {   // stage tile it+1 + prefetch tile it+2
      *(int4*)(&pool[par ^ 1][sr][sseg * 8])      = rKv;
      *(int4*)(&pool[par ^ 1][32 + sr][sseg * 8]) = rPKv;
      *(int4*)(&pqs[par ^ 1][sr][sseg * 8])       = rPQv;
      if (it + 2 < nIter) {
        const int k02 = q0 - (it + 2) * 32, jb2 = (it + 2) * 32;
        rKv  = ((const int4*)(klp + (size_t)(k02 + sr) * 64))[sseg];
        rPKv = ((const int4*)(pkp + (size_t)(jb2 + sr) * 64))[sseg];
        rPQv = ((const int4*)(pqp + (size_t)(jb2 + sr) * 64))[sseg];
      }
    }
    __syncthreads();   // barC
  }

  // epilogue PV(nIter-1)
  {
    float fr[4];
#pragma unroll
    for (int rr = 0; rr < 4; rr++) fr[rr] = mred[wr * 16 + q16 * 4 + rr];
    bf16x8 af = *(const bf16x8*)(&ptile[wr * 16 + l16][q16 * 8]);
#pragma unroll
    for (int cs = 0; cs < 2; cs++) {
      bf16x8 bv = *(const bf16x8*)(&vt[wc * 32 + cs * 16 + l16][q16 * 8]);
      f32x4 c = octx[cs];
#pragma unroll
      for (int rr = 0; rr < 4; rr++) c[rr] *= fr[rr];
      octx[cs] = MFMA_BF16(af, bv, c, 0, 0, 0);
    }
  }

  // rowsum reduce (8 threads per row, consecutive lanes)
  {
    float s = s_part;
    s += __shfl_xor(s, 1);
    s += __shfl_xor(s, 2);
    s += __shfl_xor(s, 4);
    if ((tid & 7) == 0) rsum[aq] = s;
  }
  __syncthreads();

  for (int cs = 0; cs < 2; cs++) {
    const int d = wc * 32 + cs * 16 + l16;
    for (int rr = 0; rr < 4; rr++) {
      const int qh = wr * 16 + q16 * 4 + rr;
      const float val = octx[cs][rr] / rsum[qh];
      out[((size_t)(b * 512 + q0 + qh)) * 1024 + h * 64 + d] = val;
    }
  }
}

// ---------------------------------------------------------------------------
extern "C" void kernel_launch(void* const* d_in, const int* in_sizes, int n_in,
                              void* d_out, int out_size, void* d_ws, size_t ws_size,
                              hipStream_t stream) {
  const float* q   = (const float*)d_in[0];
  const float* k   = (const float*)d_in[1];
  const float* v   = (const float*)d_in[2];
  // d_in[3] = attention_mask: deterministic causal tril -> not read
  const float* Wq  = (const float*)d_in[4];
  const float* bq  = (const float*)d_in[5];
  const float* Wk  = (const float*)d_in[6];
  const float* bk  = (const float*)d_in[7];
  const float* Wv  = (const float*)d_in[8];
  const float* bv  = (const float*)d_in[9];
  const float* Wpk = (const float*)d_in[10];
  const float* bpk = (const float*)d_in[11];
  const float* Wpq = (const float*)d_in[12];
  const float* bpq = (const float*)d_in[13];
  const float* rel = (const float*)d_in[14];
  float* out = (float*)d_out;

  char* ws = (char*)d_ws;
  const size_t MB = 1u << 20;
  __hip_bfloat16* bqi  = (__hip_bfloat16*)(ws);
  __hip_bfloat16* bki  = (__hip_bfloat16*)(ws + 8 * MB);
  __hip_bfloat16* bvi  = (__hip_bfloat16*)(ws + 16 * MB);
  __hip_bfloat16* bWq  = (__hip_bfloat16*)(ws + 24 * MB);
  __hip_bfloat16* bWk  = (__hip_bfloat16*)(ws + 26 * MB);
  __hip_bfloat16* bWv  = (__hip_bfloat16*)(ws + 28 * MB);
  __hip_bfloat16* bWpk = (__hip_bfloat16*)(ws + 30 * MB);
  __hip_bfloat16* bWpq = (__hip_bfloat16*)(ws + 32 * MB);
  __hip_bfloat16* brel = (__hip_bfloat16*)(ws + 34 * MB);
  __hip_bfloat16* wql  = (__hip_bfloat16*)(ws + 35 * MB);
  __hip_bfloat16* wkl  = (__hip_bfloat16*)(ws + 43 * MB);
  __hip_bfloat16* wvlT = (__hip_bfloat16*)(ws + 51 * MB);
  __hip_bfloat16* wpk  = (__hip_bfloat16*)(ws + 59 * MB);
  __hip_bfloat16* wpq  = (__hip_bfloat16*)(ws + 60 * MB);

  CvtArgs ca;
  ca.j[0] = { q,   bqi,  4194304 / 4 };
  ca.j[1] = { k,   bki,  4194304 / 4 };
  ca.j[2] = { v,   bvi,  4194304 / 4 };
  ca.j[3] = { Wq,  bWq,  1048576 / 4 };
  ca.j[4] = { Wk,  bWk,  1048576 / 4 };
  ca.j[5] = { Wv,  bWv,  1048576 / 4 };
  ca.j[6] = { Wpk, bWpk, 1048576 / 4 };
  ca.j[7] = { Wpq, bWpq, 1048576 / 4 };
  ca.j[8] = { rel + (size_t)512 * 1024, brel, 524288 / 4 };
  cvt_kernel<<<dim3(1024, 9), 256, 0, stream>>>(ca);

  ProjArgs pj;
  // 256x128 tiles: nBlk = (M/256) * (N/128), mBits = log2(M/256)
  pj.g[0] = { bqi,  bWq,  bq,  wql,  0, 4, 128, SCALE };  // Q pre-scaled
  pj.g[1] = { bki,  bWk,  bk,  wkl,  0, 4, 128, 1.0f };
  pj.g[2] = { bWv,  bvi,  bv,  wvlT, 1, 2, 128, 1.0f };   // operand-swapped V (M=1024, N=4096)
  pj.g[3] = { brel, bWpk, bpk, wpk,  2, 1, 16,  1.0f };
  pj.g[4] = { brel, bWpq, bpq, wpq,  2, 1, 16,  SCALE };  // pq pre-scaled
  proj_kernel<<<dim3(128, 5), 512, 0, stream>>>(pj);

  attn_kernel<<<2048, 256, 0, stream>>>(wql, wkl, wvlT, wpk, wpq, out);
}